// Round 2
// baseline (551.496 us; speedup 1.0000x reference)
//
#include <hip/hip_runtime.h>
#include <stdint.h>

#define SDIM 16384   // H*W
#define CDIM 256
#define NHEAD 8
#define BATCH 16

// Workspace layout (total < 150 KB — safe for any plausible ws_size):
//   wq    : 2048 f32 @ 0        (wq[c*8+h] = Wk[:,h*64:+64] · q[h])
//   bq    : 8 f32    @ 8192 B
//   tglob : 32768 f32 @ 16384 B (t[b,h,c] = sum_s e_s * kv[s][c], atomically)
//   z     : 128 f32  @ 16384+131072 B (z[b,h] = sum_s e_s)

// K1: prep wq/bq and zero the accumulators. grid 8 x 256.
__global__ __launch_bounds__(256) void k_prep(const float* __restrict__ Wk,
                                              const float* __restrict__ bk,
                                              const float* __restrict__ q,
                                              float* __restrict__ wq,
                                              float* __restrict__ bq,
                                              float* __restrict__ zero_region) {
    int idx = blockIdx.x * 256 + threadIdx.x;   // 0..2047
    int c = idx >> 3, h = idx & 7;
    float s = 0.f;
    for (int d = 0; d < 64; ++d)
        s += Wk[c * 512 + h * 64 + d] * q[h * 64 + d];
    wq[c * 8 + h] = s;                          // layout [c][h]
    if (idx < 8) {
        float sb = 0.f;
        for (int d = 0; d < 64; ++d)
            sb += bk[idx * 64 + d] * q[idx * 64 + d];
        bq[idx] = sb;
    }
    // zero tglob (32768) + z (128) = 32896 floats
    for (int j = idx; j < 32896; j += 2048) zero_region[j] = 0.f;
}

// K2: fused scores -> exp -> (z, t) accumulation. grid = 16*64 blocks, 256 thr.
// Block handles pixels [sc*256, sc*256+256) of batch b.
// Phase A: one pixel per thread, stream kv row (float4), dot with wq -> e[h].
// Phase B: channel-major re-read of the (L2-hot) tile, weighted accumulate.
__global__ __launch_bounds__(256) void k_main(const float* __restrict__ kv,
                                              const float* __restrict__ wq_g,
                                              const float* __restrict__ bq_g,
                                              float* __restrict__ tglob,
                                              float* __restrict__ zglob) {
    __shared__ float wq_lds[2048];      // [c][h], 8 KB
    __shared__ float pl[256 * 8];       // e[s_local][h], 8 KB
    __shared__ float red[4 * 64 * 33];  // partial-acc reduce, ~33.8 KB
    int t = threadIdx.x;
    int b = blockIdx.x >> 6, sc = blockIdx.x & 63;

    #pragma unroll
    for (int j = 0; j < 8; ++j) wq_lds[t + j * 256] = wq_g[t + j * 256];
    __syncthreads();

    // ---- Phase A: scores + exp ----
    int pix = (b << 14) + sc * 256 + t;
    const float4* row = (const float4*)(kv + (size_t)pix * CDIM); // 64 x float4
    float acc[8] = {0.f,0.f,0.f,0.f,0.f,0.f,0.f,0.f};
    for (int j = 0; j < 64; ++j) {
        float4 g = row[j];
        float kvf[4] = {g.x, g.y, g.z, g.w};
        #pragma unroll
        for (int e = 0; e < 4; ++e) {
            int c = j * 4 + e;
            const float4* wv4 = (const float4*)&wq_lds[c * 8];  // uniform: broadcast
            float4 w0 = wv4[0], w1 = wv4[1];
            acc[0] += kvf[e] * w0.x; acc[1] += kvf[e] * w0.y;
            acc[2] += kvf[e] * w0.z; acc[3] += kvf[e] * w0.w;
            acc[4] += kvf[e] * w1.x; acc[5] += kvf[e] * w1.y;
            acc[6] += kvf[e] * w1.z; acc[7] += kvf[e] * w1.w;
        }
    }
    // scores bounded (|s| < ~4): exp without max-subtraction is fp32-safe and
    // mathematically identical to the reference softmax.
    float e8[8];
    #pragma unroll
    for (int h = 0; h < 8; ++h) {
        e8[h] = __expf(acc[h] + bq_g[h]);
        pl[t * 8 + h] = e8[h];
    }
    // z: wave shuffle-reduce, lane 0 of each wave does the atomic
    #pragma unroll
    for (int h = 0; h < 8; ++h) {
        float v = e8[h];
        for (int o = 32; o > 0; o >>= 1) v += __shfl_down(v, o);
        if ((t & 63) == 0) atomicAdd(&zglob[b * 8 + h], v);
    }
    __syncthreads();

    // ---- Phase B: t[h][c] partial accumulation ----
    int sg = t >> 6, cg = t & 63;       // sg wave-uniform
    const float* kvbase = kv + ((size_t)((b << 14) + sc * 256)) * CDIM + cg * 4;
    float tac[32];                      // [h][k], c = cg*4+k
    #pragma unroll
    for (int i = 0; i < 32; ++i) tac[i] = 0.f;

    for (int s = sg; s < 256; s += 4) {
        float4 g = *(const float4*)(kvbase + (size_t)s * CDIM);  // coalesced
        float k0 = g.x, k1 = g.y, k2 = g.z, k3 = g.w;
        const float4* pp = (const float4*)&pl[s * 8];            // uniform: broadcast
        float4 p0 = pp[0], p1 = pp[1];
        float ph[8] = {p0.x, p0.y, p0.z, p0.w, p1.x, p1.y, p1.z, p1.w};
        #pragma unroll
        for (int h = 0; h < 8; ++h) {
            tac[h * 4 + 0] += k0 * ph[h];
            tac[h * 4 + 1] += k1 * ph[h];
            tac[h * 4 + 2] += k2 * ph[h];
            tac[h * 4 + 3] += k3 * ph[h];
        }
    }
    #pragma unroll
    for (int i = 0; i < 32; ++i)
        red[sg * 2112 + cg * 33 + i] = tac[i];   // +1-pad rows: conflict-light
    __syncthreads();

    int c = t;
    int rrow = (c >> 2) * 33 + (c & 3);
    #pragma unroll
    for (int h = 0; h < 8; ++h) {
        float v = red[0 * 2112 + rrow + h * 4] + red[1 * 2112 + rrow + h * 4]
                + red[2 * 2112 + rrow + h * 4] + red[3 * 2112 + rrow + h * 4];
        atomicAdd(&tglob[(size_t)(b * 8 + h) * 256 + c], v);
    }
}

// K3: out[b,h,d] = (sum_c t[b,h,c]*Wv[c,h*64+d]) / z[b,h] + bv[h*64+d]
__global__ __launch_bounds__(64) void k_out(const float* __restrict__ tglob,
                                            const float* __restrict__ zglob,
                                            const float* __restrict__ Wv,
                                            const float* __restrict__ bv,
                                            float* __restrict__ out) {
    int bh = blockIdx.x;                // b*8+h
    int h = bh & 7, d = threadIdx.x;
    const float* tr = tglob + (size_t)bh * 256;
    float acc = 0.f;
    for (int c = 0; c < 256; ++c)
        acc += tr[c] * Wv[c * 512 + h * 64 + d];
    out[bh * 64 + d] = acc / zglob[bh] + bv[h * 64 + d];
}

extern "C" void kernel_launch(void* const* d_in, const int* in_sizes, int n_in,
                              void* d_out, int out_size, void* d_ws, size_t ws_size,
                              hipStream_t stream) {
    const float* kv = (const float*)d_in[0];
    const float* Wk = (const float*)d_in[1];
    const float* bk = (const float*)d_in[2];
    const float* Wv = (const float*)d_in[3];
    const float* bv = (const float*)d_in[4];
    const float* q  = (const float*)d_in[5];

    char* ws = (char*)d_ws;
    float* wq    = (float*)(ws);                  // 2048 f32
    float* bq    = (float*)(ws + 8192);           // 8 f32
    float* tglob = (float*)(ws + 16384);          // 32768 f32
    float* zglob = (float*)(ws + 16384 + 131072); // 128 f32

    k_prep<<<8,    256, 0, stream>>>(Wk, bk, q, wq, bq, tglob /* zeroes t+z */);
    k_main<<<1024, 256, 0, stream>>>(kv, wq, bq, tglob, zglob);
    k_out <<<128,  64,  0, stream>>>(tglob, zglob, Wv, bv, (float*)d_out);
}

// Round 3
// 480.837 us; speedup vs baseline: 1.1470x; 1.1470x over previous
//
#include <hip/hip_runtime.h>
#include <stdint.h>

typedef unsigned short u16;
typedef unsigned int u32;

typedef __attribute__((ext_vector_type(8))) __bf16 bf16x8;
typedef __attribute__((ext_vector_type(4))) float f32x4;

#define SDIM 16384   // H*W
#define CDIM 256

__device__ __forceinline__ u16 f2bf(float f) {     // fp32 -> bf16 RNE
    union { float f; u32 i; } v; v.f = f;
    u32 r = v.i + 0x7FFFu + ((v.i >> 16) & 1u);
    return (u16)(r >> 16);
}
__device__ __forceinline__ float bf_lo(u32 w) { union { u32 i; float f; } v; v.i = w << 16;        return v.f; }
__device__ __forceinline__ float bf_hi(u32 w) { union { u32 i; float f; } v; v.i = w & 0xFFFF0000u; return v.f; }

// ---------------------------------------------------------------------------
// K1: wqb_g[h][c] = bf16( sum_d Wk[c, h*64+d] * q[h,d] ), rows h=8..15 zero.
//     bq[h] = bk[h*64:]·q[h].  Also zeroes tglob (32768 f32) + zglob (128 f32).
__global__ __launch_bounds__(256) void k_prep(const float* __restrict__ Wk,
                                              const float* __restrict__ bk,
                                              const float* __restrict__ q,
                                              u16* __restrict__ wqb_g,
                                              float* __restrict__ bq,
                                              float* __restrict__ zero_region) {
    int idx = blockIdx.x * 256 + threadIdx.x;   // 0..4095
    int h = idx >> 8, c = idx & 255;
    float s = 0.f;
    if (h < 8) {
        const float4* wp = (const float4*)(Wk + (size_t)c * 512 + h * 64);
        const float4* qp = (const float4*)(q + h * 64);
        #pragma unroll
        for (int j = 0; j < 16; ++j) {
            float4 w = wp[j], qq = qp[j];
            s += w.x * qq.x + w.y * qq.y + w.z * qq.z + w.w * qq.w;
        }
    }
    wqb_g[h * 256 + c] = f2bf(s);               // f2bf(0)==0 for pad rows
    if (idx < 8) {
        float sb = 0.f;
        for (int d = 0; d < 64; ++d) sb += bk[idx * 64 + d] * q[idx * 64 + d];
        bq[idx] = sb;
    }
    for (int j = idx; j < 32896; j += 4096) zero_region[j] = 0.f;
}

// ---------------------------------------------------------------------------
// K2: fused. Block = 64 pixels x 256 ch of batch b (grid 16*256).
//  - stage kv tile -> LDS bf16 (flat coalesced float4 reads, one HBM pass)
//  - phase A: scores via mfma_f32_16x16x32_bf16 (A=kv[px][ch], B=wq[h][ch])
//  - exp (no max-sub: scores bounded |s|<~5), z via shfl+LDS+1 atomic/head
//  - phase B: t[h][c] += e*kv from LDS, sg-split px, shfl_xor reduce, atomics
__global__ __launch_bounds__(256, 3) void k_main(const float* __restrict__ kv,
                                                 const u16* __restrict__ wqb_g,
                                                 const float* __restrict__ bq_g,
                                                 float* __restrict__ tglob,
                                                 float* __restrict__ zglob) {
    __shared__ u16 klds[64 * 264];   // [px][ch], row pad 256->264 (2-way free)
    __shared__ u16 wqb[16 * 264];    // [h16][ch], same pad
    __shared__ float pl[64 * 8];     // e[px][h]
    __shared__ float zp[4 * 8];      // per-wave z partials

    const int t = threadIdx.x;
    const int lane = t & 63;
    const int wave = t >> 6;
    const int blk = blockIdx.x;
    const int b = blk >> 8;

    // stage wqb: 512 uint4 chunks, 2 per thread
    {
        int i0 = t, i1 = t + 256;
        int h0 = i0 >> 5, k0 = i0 & 31;
        int h1 = i1 >> 5, k1 = i1 & 31;
        *(uint4*)&wqb[h0 * 264 + k0 * 8] = *(const uint4*)&wqb_g[h0 * 256 + k0 * 8];
        *(uint4*)&wqb[h1 * 264 + k1 * 8] = *(const uint4*)&wqb_g[h1 * 256 + k1 * 8];
    }

    // stage kv tile: 64 KB contiguous, float4 per thread x16, cvt->bf16
    const float4* kvp = (const float4*)(kv + ((size_t)blk << 14));
    #pragma unroll
    for (int j = 0; j < 16; ++j) {
        int f = j * 256 + t;                    // float4 index in tile
        float4 g = kvp[f];
        uint2 w;
        w.x = (u32)f2bf(g.x) | ((u32)f2bf(g.y) << 16);
        w.y = (u32)f2bf(g.z) | ((u32)f2bf(g.w) << 16);
        *(uint2*)&klds[(f >> 6) * 264 + (f & 63) * 4] = w;
    }
    __syncthreads();

    // ---- Phase A ----
    const int h16 = lane & 15, q4 = lane >> 4;
    bf16x8 bfrag[8];
    #pragma unroll
    for (int ks = 0; ks < 8; ++ks) {
        uint4 r = *(const uint4*)&wqb[h16 * 264 + ks * 32 + q4 * 8];
        bfrag[ks] = __builtin_bit_cast(bf16x8, r);
    }
    const int px0 = wave * 16;                  // wave's 16-pixel m-tile
    f32x4 acc = {0.f, 0.f, 0.f, 0.f};
    #pragma unroll
    for (int ks = 0; ks < 8; ++ks) {
        uint4 r = *(const uint4*)&klds[(px0 + h16) * 264 + ks * 32 + q4 * 8];
        bf16x8 a = __builtin_bit_cast(bf16x8, r);
        acc = __builtin_amdgcn_mfma_f32_16x16x32_bf16(a, bfrag[ks], acc, 0, 0, 0);
    }
    // C/D: col(lane&15)=h, row(q4*4+r)=px-local  [guide §3, m89-verified]
    float bqv = (h16 < 8) ? bq_g[h16] : 0.f;
    float e0 = __expf(acc[0] + bqv);
    float e1 = __expf(acc[1] + bqv);
    float e2 = __expf(acc[2] + bqv);
    float e3 = __expf(acc[3] + bqv);
    if (h16 < 8) {
        pl[(px0 + q4 * 4 + 0) * 8 + h16] = e0;
        pl[(px0 + q4 * 4 + 1) * 8 + h16] = e1;
        pl[(px0 + q4 * 4 + 2) * 8 + h16] = e2;
        pl[(px0 + q4 * 4 + 3) * 8 + h16] = e3;
    }
    float zv = e0 + e1 + e2 + e3;               // h>=8 lanes: garbage, never mixed in
    zv += __shfl_xor(zv, 16);
    zv += __shfl_xor(zv, 32);
    if (lane < 8) zp[wave * 8 + lane] = zv;
    __syncthreads();

    if (t < 8) atomicAdd(&zglob[b * 8 + t], zp[t] + zp[8 + t] + zp[16 + t] + zp[24 + t]);

    // ---- Phase B ----
    const int sg = t & 3, cg = t >> 2;          // cg: 4-channel group, sg: px interleave
    float tac[32];
    #pragma unroll
    for (int i = 0; i < 32; ++i) tac[i] = 0.f;
    #pragma unroll 4
    for (int i = 0; i < 16; ++i) {
        int px = sg + i * 4;
        uint2 kw = *(const uint2*)&klds[px * 264 + cg * 4];
        float k0 = bf_lo(kw.x), k1 = bf_hi(kw.x);
        float k2 = bf_lo(kw.y), k3 = bf_hi(kw.y);
        float4 p0 = *(const float4*)&pl[px * 8];
        float4 p1 = *(const float4*)&pl[px * 8 + 4];
        float ph[8] = {p0.x, p0.y, p0.z, p0.w, p1.x, p1.y, p1.z, p1.w};
        #pragma unroll
        for (int h = 0; h < 8; ++h) {
            tac[h * 4 + 0] += k0 * ph[h];
            tac[h * 4 + 1] += k1 * ph[h];
            tac[h * 4 + 2] += k2 * ph[h];
            tac[h * 4 + 3] += k3 * ph[h];
        }
    }
    #pragma unroll
    for (int i = 0; i < 32; ++i) {              // reduce over sg (same-wave lanes)
        tac[i] += __shfl_xor(tac[i], 1);
        tac[i] += __shfl_xor(tac[i], 2);
    }
    if (sg == 0) {
        float* tb = tglob + (size_t)b * 2048;   // [8 h][256 ch]
        #pragma unroll
        for (int h = 0; h < 8; ++h)
            #pragma unroll
            for (int k = 0; k < 4; ++k)
                atomicAdd(&tb[h * 256 + cg * 4 + k], tac[h * 4 + k]);
    }
}

// ---------------------------------------------------------------------------
// K3: out[b,h,d] = (sum_c t[b,h,c]*Wv[c,h*64+d]) / z[b,h] + bv[h*64+d]
__global__ __launch_bounds__(64) void k_out(const float* __restrict__ tglob,
                                            const float* __restrict__ zglob,
                                            const float* __restrict__ Wv,
                                            const float* __restrict__ bv,
                                            float* __restrict__ out) {
    int bh = blockIdx.x;
    int h = bh & 7, d = threadIdx.x;
    const float* tr = tglob + (size_t)bh * 256;
    const float* wv = Wv + h * 64 + d;
    float acc = 0.f;
    #pragma unroll 8
    for (int c = 0; c < 256; ++c)
        acc += tr[c] * wv[(size_t)c * 512];
    out[bh * 64 + d] = acc / zglob[bh] + bv[h * 64 + d];
}

extern "C" void kernel_launch(void* const* d_in, const int* in_sizes, int n_in,
                              void* d_out, int out_size, void* d_ws, size_t ws_size,
                              hipStream_t stream) {
    const float* kv = (const float*)d_in[0];
    const float* Wk = (const float*)d_in[1];
    const float* bk = (const float*)d_in[2];
    const float* Wv = (const float*)d_in[3];
    const float* bv = (const float*)d_in[4];
    const float* q  = (const float*)d_in[5];

    char* ws = (char*)d_ws;
    u16*   wqb_g = (u16*)(ws);                    // 8192 B
    float* bq    = (float*)(ws + 8192);           // 32 B
    float* tglob = (float*)(ws + 16384);          // 131072 B
    float* zglob = (float*)(ws + 16384 + 131072); // 512 B  (contiguous after tglob)

    k_prep<<<16,   256, 0, stream>>>(Wk, bk, q, wqb_g, bq, tglob /* zeroes t+z */);
    k_main<<<4096, 256, 0, stream>>>(kv, wqb_g, bq, tglob, zglob);
    k_out <<<128,  64,  0, stream>>>(tglob, zglob, Wv, bv, (float*)d_out);
}

// Round 4
// 395.383 us; speedup vs baseline: 1.3948x; 1.2161x over previous
//
#include <hip/hip_runtime.h>
#include <stdint.h>

typedef unsigned short u16;
typedef unsigned int u32;

typedef __attribute__((ext_vector_type(8))) __bf16 bf16x8;
typedef __attribute__((ext_vector_type(4))) float f32x4;

#define SDIM 16384   // H*W
#define CDIM 256

__device__ __forceinline__ u16 f2bf(float f) {     // fp32 -> bf16 RNE
    union { float f; u32 i; } v; v.f = f;
    u32 r = v.i + 0x7FFFu + ((v.i >> 16) & 1u);
    return (u16)(r >> 16);
}
__device__ __forceinline__ float bf_lo(u32 w) { union { u32 i; float f; } v; v.i = w << 16;        return v.f; }
__device__ __forceinline__ float bf_hi(u32 w) { union { u32 i; float f; } v; v.i = w & 0xFFFF0000u; return v.f; }

// ---------------------------------------------------------------------------
// K1: wqb_g[h][c] = bf16( Wk[:,h*64:+64] · q[h] ), rows h=8..15 zero.
//     bq[h] = bk·q.  No accumulator zeroing needed (no atomics anywhere now).
__global__ __launch_bounds__(256) void k_prep(const float* __restrict__ Wk,
                                              const float* __restrict__ bk,
                                              const float* __restrict__ q,
                                              u16* __restrict__ wqb_g,
                                              float* __restrict__ bq) {
    int idx = blockIdx.x * 256 + threadIdx.x;   // 0..4095
    int h = idx >> 8, c = idx & 255;
    float s = 0.f;
    if (h < 8) {
        const float4* wp = (const float4*)(Wk + (size_t)c * 512 + h * 64);
        const float4* qp = (const float4*)(q + h * 64);
        #pragma unroll
        for (int j = 0; j < 16; ++j) {
            float4 w = wp[j], qq = qp[j];
            s += w.x * qq.x + w.y * qq.y + w.z * qq.z + w.w * qq.w;
        }
    }
    wqb_g[h * 256 + c] = f2bf(s);
    if (idx < 8) {
        float sb = 0.f;
        for (int d = 0; d < 64; ++d) sb += bk[idx * 64 + d] * q[idx * 64 + d];
        bq[idx] = sb;
    }
}

// ---------------------------------------------------------------------------
// K2: block = 4 consecutive 64-px tiles of batch b (grid 16*64 = 1024).
// Per tile: stage kv->LDS bf16, MFMA scores, exp, accumulate t/z in REGISTERS
// across tiles. Epilogue: plain coalesced stores of the private partial.
// NO global atomics (round-3 lesson: 256-way contended device-scope atomics
// cost ~30 us/block of serialized cross-XCD RMW).
__global__ __launch_bounds__(256, 3) void k_main(const float* __restrict__ kv,
                                                 const u16* __restrict__ wqb_g,
                                                 const float* __restrict__ bq_g,
                                                 float* __restrict__ partials,
                                                 float* __restrict__ zpart) {
    __shared__ u16 klds[64 * 264];   // [px][ch], row pad 256->264
    __shared__ u16 wqb[16 * 264];    // [h16][ch]
    __shared__ float pl[64 * 8];     // e[px][h]
    __shared__ float zp[4 * 8];      // per-wave z partials

    const int t = threadIdx.x;
    const int lane = t & 63;
    const int wave = t >> 6;
    const int blk = blockIdx.x;
    const int b = blk >> 6, grp = blk & 63;

    // stage wqb once
    {
        int i0 = t, i1 = t + 256;
        int h0 = i0 >> 5, k0 = i0 & 31;
        int h1 = i1 >> 5, k1 = i1 & 31;
        *(uint4*)&wqb[h0 * 264 + k0 * 8] = *(const uint4*)&wqb_g[h0 * 256 + k0 * 8];
        *(uint4*)&wqb[h1 * 264 + k1 * 8] = *(const uint4*)&wqb_g[h1 * 256 + k1 * 8];
    }
    __syncthreads();

    // preload B fragments (wq) once
    const int h16 = lane & 15, q4 = lane >> 4;
    bf16x8 bfrag[8];
    #pragma unroll
    for (int ks = 0; ks < 8; ++ks) {
        uint4 r = *(const uint4*)&wqb[h16 * 264 + ks * 32 + q4 * 8];
        bfrag[ks] = __builtin_bit_cast(bf16x8, r);
    }
    const float bqv = (h16 < 8) ? bq_g[h16] : 0.f;
    const int px0 = wave * 16;
    const int sg = t & 3, cg = t >> 2;

    float tac[32];                   // t-partial [h][k], c = cg*4+k
    #pragma unroll
    for (int i = 0; i < 32; ++i) tac[i] = 0.f;
    float zacc = 0.f;                // per-lane z[h16] accumulator

    const size_t pixbase = (size_t)(b << 14) + grp * 256;

    for (int it = 0; it < 4; ++it) {
        // ---- stage 64-px tile -> LDS bf16 (coalesced float4) ----
        const float4* kvp = (const float4*)(kv + (pixbase + it * 64) * CDIM);
        #pragma unroll
        for (int j = 0; j < 16; ++j) {
            int f = j * 256 + t;
            float4 g = kvp[f];
            uint2 w;
            w.x = (u32)f2bf(g.x) | ((u32)f2bf(g.y) << 16);
            w.y = (u32)f2bf(g.z) | ((u32)f2bf(g.w) << 16);
            *(uint2*)&klds[(f >> 6) * 264 + (f & 63) * 4] = w;
        }
        __syncthreads();

        // ---- phase A: scores via MFMA, exp, pl ----
        f32x4 acc = {0.f, 0.f, 0.f, 0.f};
        #pragma unroll
        for (int ks = 0; ks < 8; ++ks) {
            uint4 r = *(const uint4*)&klds[(px0 + h16) * 264 + ks * 32 + q4 * 8];
            bf16x8 a = __builtin_bit_cast(bf16x8, r);
            acc = __builtin_amdgcn_mfma_f32_16x16x32_bf16(a, bfrag[ks], acc, 0, 0, 0);
        }
        float e0 = __expf(acc[0] + bqv);
        float e1 = __expf(acc[1] + bqv);
        float e2 = __expf(acc[2] + bqv);
        float e3 = __expf(acc[3] + bqv);
        if (h16 < 8) {
            pl[(px0 + q4 * 4 + 0) * 8 + h16] = e0;
            pl[(px0 + q4 * 4 + 1) * 8 + h16] = e1;
            pl[(px0 + q4 * 4 + 2) * 8 + h16] = e2;
            pl[(px0 + q4 * 4 + 3) * 8 + h16] = e3;
        }
        float zv = e0 + e1 + e2 + e3;
        zv += __shfl_xor(zv, 16);
        zv += __shfl_xor(zv, 32);
        zacc += zv;                  // valid for lanes with h16<8
        __syncthreads();

        // ---- phase B: tac += e * kv (from LDS) ----
        #pragma unroll 4
        for (int i = 0; i < 16; ++i) {
            int px = sg + i * 4;
            uint2 kw = *(const uint2*)&klds[px * 264 + cg * 4];
            float k0 = bf_lo(kw.x), k1 = bf_hi(kw.x);
            float k2 = bf_lo(kw.y), k3 = bf_hi(kw.y);
            float4 p0 = *(const float4*)&pl[px * 8];
            float4 p1 = *(const float4*)&pl[px * 8 + 4];
            float ph[8] = {p0.x, p0.y, p0.z, p0.w, p1.x, p1.y, p1.z, p1.w};
            #pragma unroll
            for (int h = 0; h < 8; ++h) {
                tac[h * 4 + 0] += k0 * ph[h];
                tac[h * 4 + 1] += k1 * ph[h];
                tac[h * 4 + 2] += k2 * ph[h];
                tac[h * 4 + 3] += k3 * ph[h];
            }
        }
        __syncthreads();             // klds re-staged next iter
    }

    // ---- epilogue: plain stores (no atomics) ----
    if (lane < 8) zp[wave * 8 + lane] = zacc;
    __syncthreads();
    if (t < 8) zpart[blk * 8 + t] = zp[t] + zp[8 + t] + zp[16 + t] + zp[24 + t];

    #pragma unroll
    for (int i = 0; i < 32; ++i) {   // reduce over sg (same-wave lanes)
        tac[i] += __shfl_xor(tac[i], 1);
        tac[i] += __shfl_xor(tac[i], 2);
    }
    if (sg == 0) {
        float* pb = partials + (size_t)blk * 2048;   // [8 h][256 ch]
        #pragma unroll
        for (int h = 0; h < 8; ++h) {
            float4 v = {tac[h * 4 + 0], tac[h * 4 + 1], tac[h * 4 + 2], tac[h * 4 + 3]};
            *(float4*)&pb[h * 256 + cg * 4] = v;
        }
    }
}

// ---------------------------------------------------------------------------
// K3: per (b,h): t[c] = sum_j partials, z = sum_j zpart, then
//     out[b,h,d] = (sum_c t[c]*Wv[c,h*64+d]) / z + bv[h*64+d]
__global__ __launch_bounds__(256) void k_out(const float* __restrict__ partials,
                                             const float* __restrict__ zpart,
                                             const float* __restrict__ Wv,
                                             const float* __restrict__ bv,
                                             float* __restrict__ out) {
    __shared__ float tlds[256];
    __shared__ float zsh;
    int bh = blockIdx.x;
    int b = bh >> 3, h = bh & 7, t = threadIdx.x;

    const float* p = partials + (size_t)(b * 64) * 2048 + h * 256 + t;
    float s = 0.f;
    #pragma unroll 8
    for (int j = 0; j < 64; ++j) s += p[(size_t)j * 2048];
    tlds[t] = s;

    if (t < 64) {
        float zv = zpart[(b * 64 + t) * 8 + h];
        #pragma unroll
        for (int o = 32; o > 0; o >>= 1) zv += __shfl_xor(zv, o);
        if (t == 0) zsh = zv;
    }
    __syncthreads();

    if (t < 64) {
        int d = t;
        const float* wv = Wv + h * 64 + d;
        float acc = 0.f;
        #pragma unroll 8
        for (int c = 0; c < 256; ++c)
            acc += tlds[c] * wv[(size_t)c * 512];
        out[bh * 64 + d] = acc / zsh + bv[h * 64 + d];
    }
}

extern "C" void kernel_launch(void* const* d_in, const int* in_sizes, int n_in,
                              void* d_out, int out_size, void* d_ws, size_t ws_size,
                              hipStream_t stream) {
    const float* kv = (const float*)d_in[0];
    const float* Wk = (const float*)d_in[1];
    const float* bk = (const float*)d_in[2];
    const float* Wv = (const float*)d_in[3];
    const float* bv = (const float*)d_in[4];
    const float* q  = (const float*)d_in[5];

    char* ws = (char*)d_ws;
    u16*   wqb_g    = (u16*)(ws);                        // 8 KB
    float* bq       = (float*)(ws + 8192);               // 32 B
    float* partials = (float*)(ws + 16384);              // 1024*2048 f32 = 8 MB
    float* zpart    = (float*)(ws + 16384 + 8388608);    // 1024*8 f32 = 32 KB

    k_prep<<<16,   256, 0, stream>>>(Wk, bk, q, wqb_g, bq);
    k_main<<<1024, 256, 0, stream>>>(kv, wqb_g, bq, partials, zpart);
    k_out <<<128,  256, 0, stream>>>(partials, zpart, Wv, bv, (float*)d_out);
}

// Round 5
// 388.849 us; speedup vs baseline: 1.4183x; 1.0168x over previous
//
#include <hip/hip_runtime.h>
#include <stdint.h>

typedef unsigned short u16;
typedef unsigned int u32;

typedef __attribute__((ext_vector_type(8))) __bf16 bf16x8;
typedef __attribute__((ext_vector_type(4))) float f32x4;

#define SDIM 16384   // H*W
#define CDIM 256

// async global->LDS DMA, 16 B per lane, dest = uniform base + lane*16
#define GLD_LDS16(g, l)                                                        \
    __builtin_amdgcn_global_load_lds(                                          \
        (__attribute__((address_space(1))) const void*)(g),                    \
        (__attribute__((address_space(3))) void*)(l), 16, 0, 0)

__device__ __forceinline__ u16 f2bf(float f) {     // fp32 -> bf16 RNE
    union { float f; u32 i; } v; v.f = f;
    u32 r = v.i + 0x7FFFu + ((v.i >> 16) & 1u);
    return (u16)(r >> 16);
}
__device__ __forceinline__ u32 pkbf(float a, float b) {
    return (u32)f2bf(a) | ((u32)f2bf(b) << 16);
}

// ---------------------------------------------------------------------------
// K1: wqb_g[h][c] = bf16( Wk[:,h*64:+64] · q[h] ), rows h=8..15 zero. bq = bk·q.
__global__ __launch_bounds__(256) void k_prep(const float* __restrict__ Wk,
                                              const float* __restrict__ bk,
                                              const float* __restrict__ q,
                                              u16* __restrict__ wqb_g,
                                              float* __restrict__ bq) {
    int idx = blockIdx.x * 256 + threadIdx.x;   // 0..4095
    int h = idx >> 8, c = idx & 255;
    float s = 0.f;
    if (h < 8) {
        const float4* wp = (const float4*)(Wk + (size_t)c * 512 + h * 64);
        const float4* qp = (const float4*)(q + h * 64);
        #pragma unroll
        for (int j = 0; j < 16; ++j) {
            float4 w = wp[j], qq = qp[j];
            s += w.x * qq.x + w.y * qq.y + w.z * qq.z + w.w * qq.w;
        }
    }
    wqb_g[h * 256 + c] = f2bf(s);
    if (idx < 8) {
        float sb = 0.f;
        for (int d = 0; d < 64; ++d) sb += bk[idx * 64 + d] * q[idx * 64 + d];
        bq[idx] = sb;
    }
}

// ---------------------------------------------------------------------------
// K2: block = 4 consecutive 64-px tiles of batch b (grid 16*64 = 1024).
// Staging: global_load_lds fp32 (async DMA, no VGPR round-trip — round-4
// lesson: VGPR-starved staging capped in-flight loads at ~4/thread -> <1 B/cy/CU).
// LDS layout is XOR-swizzled at 16B-chunk granularity (chunk c4 of row px lives
// at c4^px) to break bank conflicts that the unpadded DMA layout would cause.
// Phase A: MFMA scores (fp32->bf16 at fragment build). Phase B: fp32 FMA.
// t/z accumulate in registers across tiles; plain stores (no atomics).
__global__ __launch_bounds__(256, 2) void k_main(const float* __restrict__ kv,
                                                 const u16* __restrict__ wqb_g,
                                                 const float* __restrict__ bq_g,
                                                 float* __restrict__ partials,
                                                 float* __restrict__ zpart) {
    __shared__ float klds[64 * 256];  // [px][ch] fp32, XOR-swizzled chunks, 64 KB
    __shared__ u16 wqb[16 * 264];     // [h16][ch] bf16, padded
    __shared__ float pl[64 * 8];      // e[px][h]
    __shared__ float zp[4 * 8];

    const int t = threadIdx.x;
    const int lane = t & 63;
    const int wave = t >> 6;
    const int blk = blockIdx.x;
    const int b = blk >> 6, grp = blk & 63;

    // stage wqb once
    {
        int i0 = t, i1 = t + 256;
        int h0 = i0 >> 5, k0 = i0 & 31;
        int h1 = i1 >> 5, k1 = i1 & 31;
        *(uint4*)&wqb[h0 * 264 + k0 * 8] = *(const uint4*)&wqb_g[h0 * 256 + k0 * 8];
        *(uint4*)&wqb[h1 * 264 + k1 * 8] = *(const uint4*)&wqb_g[h1 * 256 + k1 * 8];
    }
    __syncthreads();

    // preload B fragments (wq) once
    const int h16 = lane & 15, q4 = lane >> 4;
    bf16x8 bfrag[8];
    #pragma unroll
    for (int ks = 0; ks < 8; ++ks) {
        uint4 r = *(const uint4*)&wqb[h16 * 264 + ks * 32 + q4 * 8];
        bfrag[ks] = __builtin_bit_cast(bf16x8, r);
    }
    const float bqv = (h16 < 8) ? bq_g[h16] : 0.f;
    const int px0 = wave * 16;
    const int arow = px0 + h16;
    const int sg = lane & 3, cg = t >> 2;

    float tac[32];                    // t-partial [h][k], c = cg*4+k
    #pragma unroll
    for (int i = 0; i < 32; ++i) tac[i] = 0.f;
    float zacc = 0.f;

    const size_t pixbase = (size_t)(b << 14) + grp * 256;

    for (int it = 0; it < 4; ++it) {
        // ---- async stage 64-px fp32 tile -> LDS (XOR-swizzled) ----
        const float* tb = kv + (pixbase + it * 64) * CDIM;
        #pragma unroll
        for (int j = 0; j < 16; ++j) {
            int px = wave * 16 + j;                       // wave-uniform row
            const float* gp = tb + px * CDIM + ((lane ^ px) & 63) * 4;
            GLD_LDS16(gp, &klds[px * 256]);               // lane i -> chunk i of row
        }
        __syncthreads();   // compiler emits s_waitcnt vmcnt(0) before s_barrier

        // ---- phase A: scores via MFMA (convert fp32->bf16 at frag build) ----
        f32x4 acc = {0.f, 0.f, 0.f, 0.f};
        #pragma unroll
        for (int ks = 0; ks < 8; ++ks) {
            int c4 = ks * 8 + q4 * 2;
            float4 fa = *(const float4*)&klds[arow * 256 + ((c4 ^ arow) & 63) * 4];
            float4 fb = *(const float4*)&klds[arow * 256 + (((c4 + 1) ^ arow) & 63) * 4];
            uint4 r;
            r.x = pkbf(fa.x, fa.y); r.y = pkbf(fa.z, fa.w);
            r.z = pkbf(fb.x, fb.y); r.w = pkbf(fb.z, fb.w);
            acc = __builtin_amdgcn_mfma_f32_16x16x32_bf16(
                      __builtin_bit_cast(bf16x8, r), bfrag[ks], acc, 0, 0, 0);
        }
        float e0 = __expf(acc[0] + bqv);
        float e1 = __expf(acc[1] + bqv);
        float e2 = __expf(acc[2] + bqv);
        float e3 = __expf(acc[3] + bqv);
        if (h16 < 8) {
            pl[(px0 + q4 * 4 + 0) * 8 + h16] = e0;
            pl[(px0 + q4 * 4 + 1) * 8 + h16] = e1;
            pl[(px0 + q4 * 4 + 2) * 8 + h16] = e2;
            pl[(px0 + q4 * 4 + 3) * 8 + h16] = e3;
        }
        float zv = e0 + e1 + e2 + e3;
        zv += __shfl_xor(zv, 16);
        zv += __shfl_xor(zv, 32);
        zacc += zv;                   // valid for lanes with h16<8
        __syncthreads();

        // ---- phase B: tac += e * kv (fp32 from swizzled LDS) ----
        #pragma unroll 4
        for (int i = 0; i < 16; ++i) {
            int px = sg + i * 4;
            float4 kw = *(const float4*)&klds[px * 256 + ((cg ^ px) & 63) * 4];
            float4 p0 = *(const float4*)&pl[px * 8];
            float4 p1 = *(const float4*)&pl[px * 8 + 4];
            float ph[8] = {p0.x, p0.y, p0.z, p0.w, p1.x, p1.y, p1.z, p1.w};
            #pragma unroll
            for (int h = 0; h < 8; ++h) {
                tac[h * 4 + 0] += kw.x * ph[h];
                tac[h * 4 + 1] += kw.y * ph[h];
                tac[h * 4 + 2] += kw.z * ph[h];
                tac[h * 4 + 3] += kw.w * ph[h];
            }
        }
        __syncthreads();              // klds re-staged next iter
    }

    // ---- epilogue: plain stores ----
    if (lane < 8) zp[wave * 8 + lane] = zacc;
    __syncthreads();
    if (t < 8) zpart[blk * 8 + t] = zp[t] + zp[8 + t] + zp[16 + t] + zp[24 + t];

    #pragma unroll
    for (int i = 0; i < 32; ++i) {    // reduce over sg (same-wave lanes)
        tac[i] += __shfl_xor(tac[i], 1);
        tac[i] += __shfl_xor(tac[i], 2);
    }
    if (sg == 0) {
        float* pb = partials + (size_t)blk * 2048;   // [8 h][256 ch]
        #pragma unroll
        for (int h = 0; h < 8; ++h) {
            float4 v = {tac[h * 4 + 0], tac[h * 4 + 1], tac[h * 4 + 2], tac[h * 4 + 3]};
            *(float4*)&pb[h * 256 + cg * 4] = v;
        }
    }
}

// ---------------------------------------------------------------------------
// K3: per (b,h): t[c] = sum_j partials, z = sum_j zpart, then
//     out[b,h,d] = (sum_c t[c]*Wv[c,h*64+d]) / z + bv[h*64+d]
__global__ __launch_bounds__(256) void k_out(const float* __restrict__ partials,
                                             const float* __restrict__ zpart,
                                             const float* __restrict__ Wv,
                                             const float* __restrict__ bv,
                                             float* __restrict__ out) {
    __shared__ float tlds[256];
    __shared__ float zsh;
    int bh = blockIdx.x;
    int b = bh >> 3, h = bh & 7, t = threadIdx.x;

    const float* p = partials + (size_t)(b * 64) * 2048 + h * 256 + t;
    float s = 0.f;
    #pragma unroll 8
    for (int j = 0; j < 64; ++j) s += p[(size_t)j * 2048];
    tlds[t] = s;

    if (t < 64) {
        float zv = zpart[(b * 64 + t) * 8 + h];
        #pragma unroll
        for (int o = 32; o > 0; o >>= 1) zv += __shfl_xor(zv, o);
        if (t == 0) zsh = zv;
    }
    __syncthreads();

    if (t < 64) {
        int d = t;
        const float* wv = Wv + h * 64 + d;
        float acc = 0.f;
        #pragma unroll 8
        for (int c = 0; c < 256; ++c)
            acc += tlds[c] * wv[(size_t)c * 512];
        out[bh * 64 + d] = acc / zsh + bv[h * 64 + d];
    }
}

extern "C" void kernel_launch(void* const* d_in, const int* in_sizes, int n_in,
                              void* d_out, int out_size, void* d_ws, size_t ws_size,
                              hipStream_t stream) {
    const float* kv = (const float*)d_in[0];
    const float* Wk = (const float*)d_in[1];
    const float* bk = (const float*)d_in[2];
    const float* Wv = (const float*)d_in[3];
    const float* bv = (const float*)d_in[4];
    const float* q  = (const float*)d_in[5];

    char* ws = (char*)d_ws;
    u16*   wqb_g    = (u16*)(ws);                        // 8 KB
    float* bq       = (float*)(ws + 8192);               // 32 B
    float* partials = (float*)(ws + 16384);              // 1024*2048 f32 = 8 MB
    float* zpart    = (float*)(ws + 16384 + 8388608);    // 1024*8 f32 = 32 KB

    k_prep<<<16,   256, 0, stream>>>(Wk, bk, q, wqb_g, bq);
    k_main<<<1024, 256, 0, stream>>>(kv, wqb_g, bq, partials, zpart);
    k_out <<<128,  256, 0, stream>>>(partials, zpart, Wv, bv, (float*)d_out);
}